// Round 10
// baseline (109.912 us; speedup 1.0000x reference)
//
#include <hip/hip_runtime.h>
#include <hip/hip_bf16.h>
#include <stdint.h>

// ---------------------------------------------------------------------------
// DAReLoss: SupCon(reparam features) + JSD(normalized Gaussian stats)
// B=4096, D=512, N=2B=8192, TAU=1, LAM=1
// Round 10: spill-free MX-fp8 sim GEMM. r8 was numerically correct but spilled
// (VGPR cap 128 with acc64+av32+bv32). Fix: 8 waves, wave tile 64x32 ->
// acc 4x2 (32) + av[4] (32) + bv[2] (16) ~= 110 VGPR. Everything else
// (swizzle, scale operands, 65-slot reduction) byte-identical to r8 (passed).
// ---------------------------------------------------------------------------

typedef __attribute__((ext_vector_type(4))) float f32x4;
typedef __attribute__((ext_vector_type(8))) int   i32x8;

#define NG 4            // K groups of 128

// ----------------------------- threefry-2x32 -------------------------------
__device__ __forceinline__ void tf_round(uint32_t& x0, uint32_t& x1, int r){
  x0 += x1;
  x1 = (x1 << r) | (x1 >> (32 - r));
  x1 ^= x0;
}

__device__ __forceinline__ void threefry2x32(uint32_t k0, uint32_t k1,
                                             uint32_t c0, uint32_t c1,
                                             uint32_t& o0, uint32_t& o1){
  uint32_t ks2 = k0 ^ k1 ^ 0x1BD11BDAu;
  uint32_t x0 = c0 + k0, x1 = c1 + k1;
  tf_round(x0,x1,13); tf_round(x0,x1,15); tf_round(x0,x1,26); tf_round(x0,x1,6);
  x0 += k1; x1 += ks2 + 1u;
  tf_round(x0,x1,17); tf_round(x0,x1,29); tf_round(x0,x1,16); tf_round(x0,x1,24);
  x0 += ks2; x1 += k0 + 2u;
  tf_round(x0,x1,13); tf_round(x0,x1,15); tf_round(x0,x1,26); tf_round(x0,x1,6);
  x0 += k0; x1 += k1 + 3u;
  tf_round(x0,x1,17); tf_round(x0,x1,29); tf_round(x0,x1,16); tf_round(x0,x1,24);
  x0 += k1; x1 += ks2 + 4u;
  tf_round(x0,x1,13); tf_round(x0,x1,15); tf_round(x0,x1,26); tf_round(x0,x1,6);
  x0 += ks2; x1 += k0 + 5u;
  o0 = x0; o1 = x1;
}

__device__ __forceinline__ float erfinv_f32(float x){
  float w = -log1pf(-x*x);
  float p;
  if (w < 5.0f){
    w -= 2.5f;
    p = 2.81022636e-08f;
    p = fmaf(p,w, 3.43273939e-07f);
    p = fmaf(p,w,-3.5233877e-06f);
    p = fmaf(p,w,-4.39150654e-06f);
    p = fmaf(p,w, 0.00021858087f);
    p = fmaf(p,w,-0.00125372503f);
    p = fmaf(p,w,-0.00417768164f);
    p = fmaf(p,w, 0.246640727f);
    p = fmaf(p,w, 1.50140941f);
  } else {
    w = sqrtf(w) - 3.0f;
    p = -0.000200214257f;
    p = fmaf(p,w, 0.000100950558f);
    p = fmaf(p,w, 0.00134934322f);
    p = fmaf(p,w,-0.00367342844f);
    p = fmaf(p,w, 0.00573950773f);
    p = fmaf(p,w,-0.0076224613f);
    p = fmaf(p,w, 0.00943887047f);
    p = fmaf(p,w, 1.00167406f);
    p = fmaf(p,w, 2.83297682f);
  }
  return p*x;
}

__device__ __forceinline__ float bits2normal(uint32_t bits){
  float f = __uint_as_float((bits >> 9) | 0x3F800000u) - 1.0f;   // [0,1)
  const float lo = -0.99999994f;
  float v = fmaf(f, 2.0f, lo);
  v = fmaxf(lo, v);
  return 1.41421354f * erfinv_f32(v);
}

// f32 -> OCP e4m3fn, RNE (verified: r8 passed with this).
__device__ __forceinline__ unsigned char f2e4m3(float x){
  float ax = fabsf(x);
  unsigned int s = (__float_as_uint(x) >> 24) & 0x80u;
  if (ax < 0.015625f){
    unsigned int q = (unsigned int)__float2int_rn(ax * 512.0f);
    return (unsigned char)(s | q);
  }
  if (ax > 448.0f) return (unsigned char)(s | 0x7E);
  unsigned int u = __float_as_uint(ax);
  u += 0x7FFFFu + ((u >> 20) & 1u);
  unsigned int e = (u >> 23) - 127u + 7u;
  return (unsigned char)(s | (e << 3) | ((u >> 20) & 7u));
}

// ------------------- K1: features + normalize + JSD (fused) ----------------
// 2048 blocks; block handles batch rows r and r+2048 (threefry pair-sharing).
__global__ __launch_bounds__(256) void k_featsjsd(const float* __restrict__ mu,
                                                  const float* __restrict__ mu_cap,
                                                  const float* __restrict__ lv,
                                                  const float* __restrict__ lv_cap,
                                                  unsigned char* __restrict__ Xn,
                                                  float* __restrict__ jsd_row){
  int r = blockIdx.x;          // 0..2047
  int t = threadIdx.x;

  uint32_t a0,a1,b0,b1;
  threefry2x32(0u, 42u, 0u, 2u, a0, b0);
  threefry2x32(0u, 42u, 1u, 3u, a1, b1);

  float m[2][2], mc[2][2], av[2][2], bv[2][2], x[2][2], xc[2][2];
  float s[2][6] = {{0,0,0,0,0,0},{0,0,0,0,0,0}};

  #pragma unroll
  for (int h = 0; h < 2; ++h){
    size_t base = (size_t)(r + h*2048) * 512;
    float2 m2  = *(const float2*)(mu     + base + 2*t);
    float2 mc2 = *(const float2*)(mu_cap + base + 2*t);
    float2 av2 = *(const float2*)(lv     + base + 2*t);
    float2 bv2 = *(const float2*)(lv_cap + base + 2*t);
    m[h][0]=m2.x;  m[h][1]=m2.y;  mc[h][0]=mc2.x; mc[h][1]=mc2.y;
    av[h][0]=av2.x; av[h][1]=av2.y; bv[h][0]=bv2.x; bv[h][1]=bv2.y;
  }

  #pragma unroll
  for (int q = 0; q < 2; ++q){
    uint32_t p = (uint32_t)r*512u + (uint32_t)(2*t + q);   // < 2^20
    uint32_t oa0, oa1, ob0, ob1;
    threefry2x32(a0, a1, p, p + 0x100000u, oa0, oa1);
    threefry2x32(b0, b1, p, p + 0x100000u, ob0, ob1);
    float e1[2] = {bits2normal(oa0), bits2normal(oa1)};
    float e2[2] = {bits2normal(ob0), bits2normal(ob1)};
    #pragma unroll
    for (int h = 0; h < 2; ++h){
      x[h][q]  = m[h][q]  + __expf(0.5f*av[h][q]) * e1[h];
      xc[h][q] = mc[h][q] + __expf(0.5f*bv[h][q]) * e2[h];
      s[h][0] += x[h][q]*x[h][q];   s[h][1] += xc[h][q]*xc[h][q];
      s[h][2] += m[h][q]*m[h][q];   s[h][3] += mc[h][q]*mc[h][q];
      s[h][4] += av[h][q]*av[h][q]; s[h][5] += bv[h][q]*bv[h][q];
    }
  }

  __shared__ float sred[4][12];
  #pragma unroll
  for (int h = 0; h < 2; ++h)
    #pragma unroll
    for (int k = 0; k < 6; ++k){
      float v = s[h][k];
      #pragma unroll
      for (int o = 32; o; o >>= 1) v += __shfl_down(v, o);
      if ((t & 63) == 0) sred[t >> 6][h*6 + k] = v;
    }
  __syncthreads();
  float tot[2][6];
  #pragma unroll
  for (int h = 0; h < 2; ++h)
    #pragma unroll
    for (int k = 0; k < 6; ++k)
      tot[h][k] = sred[0][h*6+k] + sred[1][h*6+k] + sred[2][h*6+k] + sred[3][h*6+k];

  float accv[2] = {0.f, 0.f};
  #pragma unroll
  for (int h = 0; h < 2; ++h){
    float ix  = 1.f / fmaxf(sqrtf(tot[h][0]), 1e-12f);
    float ixc = 1.f / fmaxf(sqrtf(tot[h][1]), 1e-12f);
    float im  = 1.f / fmaxf(sqrtf(tot[h][2]), 1e-12f);
    float imc = 1.f / fmaxf(sqrtf(tot[h][3]), 1e-12f);
    float ia  = 1.f / fmaxf(sqrtf(tot[h][4]), 1e-12f);
    float ib  = 1.f / fmaxf(sqrtf(tot[h][5]), 1e-12f);
    float ix16  = ix  * 16.f;
    float ixc16 = ixc * 16.f;

    unsigned char xb[2], xcb[2];
    #pragma unroll
    for (int q = 0; q < 2; ++q){
      xb[q]  = f2e4m3(x[h][q]  * ix16);
      xcb[q] = f2e4m3(xc[h][q] * ixc16);
      float an = m[h][q]*im, bn = mc[h][q]*imc;
      float al = av[h][q]*ia, bl = bv[h][q]*ib;
      float ea = __expf(al), eb = __expf(bl);
      float varm = 0.5f*(ea + eb);
      float lvm  = __logf(varm + 1e-8f);
      float v2   = __expf(lvm);
      float den  = v2 + 1e-8f;
      float dm   = 0.5f*(an - bn);
      float dm2  = dm*dm;
      accv[h] += (ea + 1e-8f)/den + (lvm - al) + dm2/den - 1.f;
      accv[h] += (eb + 1e-8f)/den + (lvm - bl) + dm2/den - 1.f;
    }
    size_t base = (size_t)(r + h*2048) * 512;
    *(unsigned short*)(Xn + base + 2*t) =
        (unsigned short)(xb[0] | ((unsigned short)xb[1] << 8));
    *(unsigned short*)(Xn + (size_t)4096*512 + base + 2*t) =
        (unsigned short)(xcb[0] | ((unsigned short)xcb[1] << 8));
  }

  __shared__ float sred2[4][2];
  #pragma unroll
  for (int h = 0; h < 2; ++h){
    float v = accv[h];
    #pragma unroll
    for (int o = 32; o; o >>= 1) v += __shfl_down(v, o);
    if ((t & 63) == 0) sred2[t >> 6][h] = v;
  }
  __syncthreads();
  if (t < 2)
    jsd_row[r + t*2048] = 0.25f * (sred2[0][t]+sred2[1][t]+sred2[2][t]+sred2[3][t]);
}

// -------------------- K2: sim = Xn Xn^T (triangular), LSE, MX-fp8 ----------
// 2080 tiles = upper triangle (i<=j), 128x128 each. 8 waves (2wr x 4wc),
// wave tile 64x32, acc 4x2 (32 VGPR) + av[4] (32) + bv[2] (16): no spill at
// the 128-VGPR cap. Ring-2 slots (32KB each), 4 gloads/wave/group. Staging
// swizzle + read addressing + scale operands byte-identical to r8 (passed).
__device__ __forceinline__ void gload_lds16(const unsigned char* g, unsigned char* l){
  __builtin_amdgcn_global_load_lds(
      (const __attribute__((address_space(1))) void*)g,
      (__attribute__((address_space(3))) void*)l, 16, 0, 0);
}

__global__ __launch_bounds__(512, 2) void k_simlse(const unsigned char* __restrict__ Xn,
                                                   float* __restrict__ rowsumP, // [128][8192]
                                                   float* __restrict__ possim){ // [8192]
  // XCD-chunked bijective swizzle: 2080 = 8*260
  int bid = (blockIdx.x & 7)*260 + (blockIdx.x >> 3);
  int id = bid, i = 0, rem = 64;
  while (id >= rem){ id -= rem; --rem; ++i; }
  int j = i + id;
  int rowbase = i*128, colbase = j*128;
  bool postile = (j == i + 32);

  __shared__ unsigned char SA[2*16384];   // 2 slots x 8 chunks x 2KB
  __shared__ unsigned char SB[2*16384];
  __shared__ float redR[4][128];
  __shared__ float redC[2][128];

  int tid = threadIdx.x;
  int wid = tid >> 6, l = tid & 63;
  int wr = wid >> 2, wc = wid & 3;        // 2 x 4 wave grid, wave tile 64x32
  int l15 = l & 15, q = l >> 4;

  // staging source pre-swizzle (bytes; identical to r8)
  int xw = (l & 7) ^ (l >> 3);
  int prow  = (l >> 3)*2 + (xw >> 2);
  int pcolb = (xw & 3) * 16;

  // frag read addressing within a 2KB chunk (identical to r8)
  int hh  = l15 >> 1;
  int x0  = ((l15 & 1) << 2) | ((q & 1) << 1);
  int w0  = hh*8 + (x0 ^ hh);
  const int rdo = (q >> 1)*1024 + w0*16;   // second read at rdo^16

  f32x4 acc[4][2];
  #pragma unroll
  for (int m = 0; m < 4; ++m)
    #pragma unroll
    for (int n = 0; n < 2; ++n) acc[m][n] = f32x4{0.f,0.f,0.f,0.f};

  // staging bases: each wave owns chunk 'wid' of A and of B (16 rows each)
  const unsigned char* gA0 = Xn + (size_t)(rowbase + wid*16 + prow)*512 + pcolb;
  const unsigned char* gB0 = Xn + (size_t)(colbase + wid*16 + prow)*512 + pcolb;

  // ---- prologue: stage group 0 -> slot 0 (4 gloads/wave) ----
  #pragma unroll
  for (int sub = 0; sub < 2; ++sub){
    gload_lds16(gA0 + sub*64, &SA[wid*2048 + sub*1024]);
    gload_lds16(gB0 + sub*64, &SB[wid*2048 + sub*1024]);
  }
  asm volatile("s_waitcnt vmcnt(0)" ::: "memory");
  __builtin_amdgcn_s_barrier();

  // ---- main loop: 4 groups of K=128 ----
  for (int g = 0; g < NG; ++g){
    int sl = g & 1;
    const unsigned char* SAb = &SA[sl*16384];
    const unsigned char* SBb = &SB[sl*16384];

    i32x8 avf[4], bvf[2];
    #pragma unroll
    for (int m = 0; m < 4; ++m){
      const unsigned char* p = SAb + (wr*4 + m)*2048;
      uint4 lo = *(const uint4*)(p + rdo);
      uint4 hi = *(const uint4*)(p + (rdo ^ 16));
      avf[m] = i32x8{(int)lo.x,(int)lo.y,(int)lo.z,(int)lo.w,
                     (int)hi.x,(int)hi.y,(int)hi.z,(int)hi.w};
    }
    #pragma unroll
    for (int n = 0; n < 2; ++n){
      const unsigned char* p = SBb + (wc*2 + n)*2048;
      uint4 lo = *(const uint4*)(p + rdo);
      uint4 hi = *(const uint4*)(p + (rdo ^ 16));
      bvf[n] = i32x8{(int)lo.x,(int)lo.y,(int)lo.z,(int)lo.w,
                     (int)hi.x,(int)hi.y,(int)hi.z,(int)hi.w};
    }

    // stage group g+1 into the other slot (readers finished at prev barrier)
    if (g + 1 < NG){
      unsigned char* dA = &SA[(sl^1)*16384];
      unsigned char* dB = &SB[(sl^1)*16384];
      #pragma unroll
      for (int sub = 0; sub < 2; ++sub){
        gload_lds16(gA0 + (g+1)*128 + sub*64, &dA[wid*2048 + sub*1024]);
        gload_lds16(gB0 + (g+1)*128 + sub*64, &dB[wid*2048 + sub*1024]);
      }
    }

    asm volatile("s_waitcnt lgkmcnt(0)" ::: "memory");
    __builtin_amdgcn_sched_barrier(0);
    __builtin_amdgcn_s_setprio(1);
    #pragma unroll
    for (int m = 0; m < 4; ++m)
      #pragma unroll
      for (int n = 0; n < 2; ++n)
        acc[m][n] = __builtin_amdgcn_mfma_scale_f32_16x16x128_f8f6f4(
            avf[m], bvf[n], acc[m][n], 0, 0, 0, 0x7F7F7F7F, 0, 0x7F7F7F7F);
    __builtin_amdgcn_s_setprio(0);

    if (g + 1 < NG){
      asm volatile("s_waitcnt vmcnt(0)" ::: "memory");
      __builtin_amdgcn_s_barrier();
    }
  }

  // ---- epilogue: /256 de-scale, c>r predicate, exp, pos-pair, sums ----
  float rsum[4][4];
  float csum[2] = {0.f, 0.f};
  #pragma unroll
  for (int m = 0; m < 4; ++m)
    #pragma unroll
    for (int rr = 0; rr < 4; ++rr) rsum[m][rr] = 0.f;

  #pragma unroll
  for (int m = 0; m < 4; ++m){
    #pragma unroll
    for (int n = 0; n < 2; ++n){
      int col_l = wc*32 + n*16 + l15;
      int c = colbase + col_l;
      #pragma unroll
      for (int rr = 0; rr < 4; ++rr){
        int row_l = wr*64 + m*16 + q*4 + rr;
        int r = rowbase + row_l;
        float v = acc[m][n][rr] * 0.00390625f;
        if (postile && row_l == col_l){
          possim[r] = v;
          possim[r + 4096] = v;
        }
        float e = (c > r) ? __expf(v) : 0.f;
        rsum[m][rr] += e;
        csum[n]     += e;
      }
    }
  }

  // row-sums: reduce across 16 col-lanes; combine 4 wc waves; slot j
  #pragma unroll
  for (int m = 0; m < 4; ++m){
    #pragma unroll
    for (int rr = 0; rr < 4; ++rr){
      float s = rsum[m][rr];
      s += __shfl_xor(s, 1); s += __shfl_xor(s, 2);
      s += __shfl_xor(s, 4); s += __shfl_xor(s, 8);
      if (l15 == 0) redR[wc][wr*64 + m*16 + q*4 + rr] = s;
    }
  }
  // col-sums: reduce across q groups; combine wr halves; slot 64+i
  #pragma unroll
  for (int n = 0; n < 2; ++n){
    float s = csum[n];
    s += __shfl_xor(s, 16); s += __shfl_xor(s, 32);
    if (q == 0) redC[wr][wc*32 + n*16 + l15] = s;
  }
  __syncthreads();
  if (tid < 128){
    rowsumP[(size_t)j*8192 + rowbase + tid] =
        redR[0][tid] + redR[1][tid] + redR[2][tid] + redR[3][tid];
    rowsumP[(size_t)(64+i)*8192 + colbase + tid] = redC[0][tid] + redC[1][tid];
  }
}

// ------------------- K3a: per-row lse partials (128 blocks) -----------------
// Row r (block br=r>>7): 65 slots = row-sums br..63 + col-sums 64..64+br.
__global__ __launch_bounds__(256) void k_lsepart(const float* __restrict__ rowsumP,
                                                 const float* __restrict__ possim,
                                                 float* __restrict__ part){
  int t = threadIdx.x;
  int row = blockIdx.x*64 + (t & 63);
  int br = row >> 7;
  int g = t >> 6;
  float s = 0.f;
  for (int cs = g; cs < 65; cs += 4){
    int slot = (cs < 64 - br) ? (br + cs) : (64 + (cs - (64 - br)));
    s += rowsumP[(size_t)slot*8192 + row];
  }
  __shared__ float partial[4][64];
  partial[g][t & 63] = s;
  __syncthreads();
  if (t < 64){
    float tot = partial[0][t] + partial[1][t] + partial[2][t] + partial[3][t];
    float v = __logf(tot) - possim[row];
    #pragma unroll
    for (int o = 32; o; o >>= 1) v += __shfl_down(v, o);
    if (t == 0) part[blockIdx.x] = v;
  }
}

// --------------------------- K3b: final combine -----------------------------
__global__ __launch_bounds__(256) void k_final(const float* __restrict__ part,
                                               const float* __restrict__ jsd_row,
                                               float* __restrict__ out){
  int t = threadIdx.x;
  float s = (t < 128) ? part[t] : 0.f;
  float j = 0.f;
  #pragma unroll
  for (int qq = 0; qq < 16; ++qq) j += jsd_row[t + qq*256];

  __shared__ float sr[4], jr[4];
  float ss = s, jj = j;
  #pragma unroll
  for (int o = 32; o; o >>= 1){ ss += __shfl_down(ss, o); jj += __shfl_down(jj, o); }
  if ((t & 63) == 0){ sr[t >> 6] = ss; jr[t >> 6] = jj; }
  __syncthreads();
  if (t == 0){
    float base = (sr[0]+sr[1]+sr[2]+sr[3]) / (8192.f * (1.f + 1e-5f));
    float jsd  = (jr[0]+jr[1]+jr[2]+jr[3]) / 4096.f;
    out[0] = base + jsd;   // LAM = 1
  }
}

// ---------------------------------------------------------------------------
extern "C" void kernel_launch(void* const* d_in, const int* in_sizes, int n_in,
                              void* d_out, int out_size, void* d_ws, size_t ws_size,
                              hipStream_t stream) {
  const float* mu     = (const float*)d_in[0];
  const float* mu_cap = (const float*)d_in[1];
  const float* lv     = (const float*)d_in[2];
  const float* lv_cap = (const float*)d_in[3];
  float* out = (float*)d_out;

  char* w = (char*)d_ws;
  unsigned char* Xn = (unsigned char*)w;                      // 8192*512 = 4 MB
  float* rowsumP = (float*)(w + 4194304);                     // 128*8192*4 = 4 MB
  float* possim  = (float*)(w + 4194304 + 4194304);           // 32 KB
  float* jsd_row = (float*)(w + 4194304 + 4194304 + 32768);   // 16 KB
  float* part    = (float*)(w + 4194304 + 4194304 + 32768 + 16384); // 512 B

  k_featsjsd<<<2048, 256, 0, stream>>>(mu, mu_cap, lv, lv_cap, Xn, jsd_row);
  k_simlse  <<<2080, 512, 0, stream>>>(Xn, rowsumP, possim);
  k_lsepart <<<128,  256, 0, stream>>>(rowsumP, possim, part);
  k_final   <<<1,    256, 0, stream>>>(part, jsd_row, out);
}

// Round 11
// 103.344 us; speedup vs baseline: 1.0636x; 1.0636x over previous
//
#include <hip/hip_runtime.h>
#include <hip/hip_bf16.h>
#include <stdint.h>

// ---------------------------------------------------------------------------
// DAReLoss: SupCon(reparam features) + JSD(normalized Gaussian stats)
// B=4096, D=512, N=2B=8192, TAU=1, LAM=1
// Round 11: r4 k_simlse + read-ahead pipelined LDS reads (m201 ordering):
// each phase's ds_reads are issued in the PREVIOUS phase before its barrier,
// so post-barrier is lgkm(counted)->MFMA with latency hidden. Alternating
// named register sets (rule #20), re-derived vmcnt ledger (6/4/0).
// K1 (threefry pair-sharing) and K3 from r9.
// ---------------------------------------------------------------------------

typedef __attribute__((ext_vector_type(4))) float f32x4;
typedef __attribute__((ext_vector_type(8))) short bf16x8;

#define NSLOT 32
#define NGK   16        // K / 32

// ----------------------------- threefry-2x32 -------------------------------
__device__ __forceinline__ void tf_round(uint32_t& x0, uint32_t& x1, int r){
  x0 += x1;
  x1 = (x1 << r) | (x1 >> (32 - r));
  x1 ^= x0;
}

__device__ __forceinline__ void threefry2x32(uint32_t k0, uint32_t k1,
                                             uint32_t c0, uint32_t c1,
                                             uint32_t& o0, uint32_t& o1){
  uint32_t ks2 = k0 ^ k1 ^ 0x1BD11BDAu;
  uint32_t x0 = c0 + k0, x1 = c1 + k1;
  tf_round(x0,x1,13); tf_round(x0,x1,15); tf_round(x0,x1,26); tf_round(x0,x1,6);
  x0 += k1; x1 += ks2 + 1u;
  tf_round(x0,x1,17); tf_round(x0,x1,29); tf_round(x0,x1,16); tf_round(x0,x1,24);
  x0 += ks2; x1 += k0 + 2u;
  tf_round(x0,x1,13); tf_round(x0,x1,15); tf_round(x0,x1,26); tf_round(x0,x1,6);
  x0 += k0; x1 += k1 + 3u;
  tf_round(x0,x1,17); tf_round(x0,x1,29); tf_round(x0,x1,16); tf_round(x0,x1,24);
  x0 += k1; x1 += ks2 + 4u;
  tf_round(x0,x1,13); tf_round(x0,x1,15); tf_round(x0,x1,26); tf_round(x0,x1,6);
  x0 += ks2; x1 += k0 + 5u;
  o0 = x0; o1 = x1;
}

__device__ __forceinline__ float erfinv_f32(float x){
  float w = -log1pf(-x*x);
  float p;
  if (w < 5.0f){
    w -= 2.5f;
    p = 2.81022636e-08f;
    p = fmaf(p,w, 3.43273939e-07f);
    p = fmaf(p,w,-3.5233877e-06f);
    p = fmaf(p,w,-4.39150654e-06f);
    p = fmaf(p,w, 0.00021858087f);
    p = fmaf(p,w,-0.00125372503f);
    p = fmaf(p,w,-0.00417768164f);
    p = fmaf(p,w, 0.246640727f);
    p = fmaf(p,w, 1.50140941f);
  } else {
    w = sqrtf(w) - 3.0f;
    p = -0.000200214257f;
    p = fmaf(p,w, 0.000100950558f);
    p = fmaf(p,w, 0.00134934322f);
    p = fmaf(p,w,-0.00367342844f);
    p = fmaf(p,w, 0.00573950773f);
    p = fmaf(p,w,-0.0076224613f);
    p = fmaf(p,w, 0.00943887047f);
    p = fmaf(p,w, 1.00167406f);
    p = fmaf(p,w, 2.83297682f);
  }
  return p*x;
}

__device__ __forceinline__ float bits2normal(uint32_t bits){
  float f = __uint_as_float((bits >> 9) | 0x3F800000u) - 1.0f;   // [0,1)
  const float lo = -0.99999994f;
  float v = fmaf(f, 2.0f, lo);
  v = fmaxf(lo, v);
  return 1.41421354f * erfinv_f32(v);
}

__device__ __forceinline__ unsigned short f2bf(float f){
  uint32_t u = __float_as_uint(f);
  u += 0x7FFFu + ((u >> 16) & 1u);   // RNE
  return (unsigned short)(u >> 16);
}

// ------------------- K1: features + normalize + JSD (fused) ----------------
__global__ __launch_bounds__(256) void k_featsjsd(const float* __restrict__ mu,
                                                  const float* __restrict__ mu_cap,
                                                  const float* __restrict__ lv,
                                                  const float* __restrict__ lv_cap,
                                                  unsigned short* __restrict__ Xn,
                                                  float* __restrict__ jsd_row){
  int r = blockIdx.x;          // 0..2047
  int t = threadIdx.x;

  uint32_t a0,a1,b0,b1;
  threefry2x32(0u, 42u, 0u, 2u, a0, b0);
  threefry2x32(0u, 42u, 1u, 3u, a1, b1);

  float m[2][2], mc[2][2], av[2][2], bv[2][2], x[2][2], xc[2][2];
  float s[2][6] = {{0,0,0,0,0,0},{0,0,0,0,0,0}};

  #pragma unroll
  for (int h = 0; h < 2; ++h){
    size_t base = (size_t)(r + h*2048) * 512;
    float2 m2  = *(const float2*)(mu     + base + 2*t);
    float2 mc2 = *(const float2*)(mu_cap + base + 2*t);
    float2 av2 = *(const float2*)(lv     + base + 2*t);
    float2 bv2 = *(const float2*)(lv_cap + base + 2*t);
    m[h][0]=m2.x;  m[h][1]=m2.y;  mc[h][0]=mc2.x; mc[h][1]=mc2.y;
    av[h][0]=av2.x; av[h][1]=av2.y; bv[h][0]=bv2.x; bv[h][1]=bv2.y;
  }

  #pragma unroll
  for (int q = 0; q < 2; ++q){
    uint32_t p = (uint32_t)r*512u + (uint32_t)(2*t + q);   // < 2^20
    uint32_t oa0, oa1, ob0, ob1;
    threefry2x32(a0, a1, p, p + 0x100000u, oa0, oa1);
    threefry2x32(b0, b1, p, p + 0x100000u, ob0, ob1);
    float e1[2] = {bits2normal(oa0), bits2normal(oa1)};
    float e2[2] = {bits2normal(ob0), bits2normal(ob1)};
    #pragma unroll
    for (int h = 0; h < 2; ++h){
      x[h][q]  = m[h][q]  + __expf(0.5f*av[h][q]) * e1[h];
      xc[h][q] = mc[h][q] + __expf(0.5f*bv[h][q]) * e2[h];
      s[h][0] += x[h][q]*x[h][q];   s[h][1] += xc[h][q]*xc[h][q];
      s[h][2] += m[h][q]*m[h][q];   s[h][3] += mc[h][q]*mc[h][q];
      s[h][4] += av[h][q]*av[h][q]; s[h][5] += bv[h][q]*bv[h][q];
    }
  }

  __shared__ float sred[4][12];
  #pragma unroll
  for (int h = 0; h < 2; ++h)
    #pragma unroll
    for (int k = 0; k < 6; ++k){
      float v = s[h][k];
      #pragma unroll
      for (int o = 32; o; o >>= 1) v += __shfl_down(v, o);
      if ((t & 63) == 0) sred[t >> 6][h*6 + k] = v;
    }
  __syncthreads();
  float tot[2][6];
  #pragma unroll
  for (int h = 0; h < 2; ++h)
    #pragma unroll
    for (int k = 0; k < 6; ++k)
      tot[h][k] = sred[0][h*6+k] + sred[1][h*6+k] + sred[2][h*6+k] + sred[3][h*6+k];

  float accv[2] = {0.f, 0.f};
  #pragma unroll
  for (int h = 0; h < 2; ++h){
    float ix  = 1.f / fmaxf(sqrtf(tot[h][0]), 1e-12f);
    float ixc = 1.f / fmaxf(sqrtf(tot[h][1]), 1e-12f);
    float im  = 1.f / fmaxf(sqrtf(tot[h][2]), 1e-12f);
    float imc = 1.f / fmaxf(sqrtf(tot[h][3]), 1e-12f);
    float ia  = 1.f / fmaxf(sqrtf(tot[h][4]), 1e-12f);
    float ib  = 1.f / fmaxf(sqrtf(tot[h][5]), 1e-12f);

    unsigned short xb[2], xcb[2];
    #pragma unroll
    for (int q = 0; q < 2; ++q){
      xb[q]  = f2bf(x[h][q]  * ix);
      xcb[q] = f2bf(xc[h][q] * ixc);
      float an = m[h][q]*im, bn = mc[h][q]*imc;
      float al = av[h][q]*ia, bl = bv[h][q]*ib;
      float ea = __expf(al), eb = __expf(bl);
      float varm = 0.5f*(ea + eb);
      float lvm  = __logf(varm + 1e-8f);
      float v2   = __expf(lvm);
      float den  = v2 + 1e-8f;
      float dm   = 0.5f*(an - bn);
      float dm2  = dm*dm;
      accv[h] += (ea + 1e-8f)/den + (lvm - al) + dm2/den - 1.f;
      accv[h] += (eb + 1e-8f)/den + (lvm - bl) + dm2/den - 1.f;
    }
    size_t base = (size_t)(r + h*2048) * 512;
    *(uint32_t*)&Xn[base + 2*t] = xb[0] | ((uint32_t)xb[1] << 16);
    *(uint32_t*)&Xn[(size_t)4096*512 + base + 2*t] = xcb[0] | ((uint32_t)xcb[1] << 16);
  }

  __shared__ float sred2[4][2];
  #pragma unroll
  for (int h = 0; h < 2; ++h){
    float v = accv[h];
    #pragma unroll
    for (int o = 32; o; o >>= 1) v += __shfl_down(v, o);
    if ((t & 63) == 0) sred2[t >> 6][h] = v;
  }
  __syncthreads();
  if (t < 2)
    jsd_row[r + t*2048] = 0.25f * (sred2[0][t]+sred2[1][t]+sred2[2][t]+sred2[3][t]);
}

// -------------------- K2: sim = Xn Xn^T (triangular), LSE ------------------
// r4 structure with read-ahead: P1(gk) pre-issues bfr/af0 of gk+1 (before
// the end-of-phase barrier), P0(gk) issues only af1(gk). Counted lgkm:
// P0 lgkm(4) [af1 in flight], P1 lgkm(8) [next-gk reads in flight].
// vmcnt ledger (audited): stage SA(g) in P0(g-3), SB(g) in P1(g-3);
// issued after P0(G) = 12+2min(G+1,13)+2min(G,13); retire through SB(G+1)
// = 4G+8 -> vmcnt(6) for G<=12, (4) G=13, (0) G=14.
__device__ __forceinline__ void gload_lds16(const unsigned short* g, unsigned short* l){
  __builtin_amdgcn_global_load_lds(
      (const __attribute__((address_space(1))) void*)g,
      (__attribute__((address_space(3))) void*)l, 16, 0, 0);
}

__device__ __forceinline__ void stage_slot(const unsigned short* __restrict__ Xn,
                                           unsigned short* S, int slot, int pbase,
                                           int gk, int wid, int prow, int pcol){
  const unsigned short* g = Xn + (size_t)(pbase + wid*32 + prow)*512 + gk*32 + pcol;
  gload_lds16(g,          &S[slot*8192 + (wid*2  )*512]);
  gload_lds16(g + 16*512, &S[slot*8192 + (wid*2+1)*512]);
}

__device__ __forceinline__ void gk_body(
    int gk, const unsigned short* __restrict__ Xn,
    unsigned short* SA, unsigned short* SB,
    int rowbase, int colbase, int wid, int prow, int pcol,
    int aoff, int boff,
    bf16x8 (&af0c)[4], bf16x8 (&bfc)[4],
    bf16x8 (&af0n)[4], bf16x8 (&bfn)[4],
    bf16x8 (&af1)[4],
    f32x4 (&acc)[8][4])
{
  const unsigned short* SAb = &SA[(gk & 3)*8192];

  // ---- P0: issue af1(gk), stage A(gk+3); M0 = af0c x bfc ----
  #pragma unroll
  for (int mi = 0; mi < 4; ++mi)
    af1[mi] = *(const bf16x8*)&SAb[aoff + 2048 + mi*512];
  if (gk + 3 < NGK)
    stage_slot(Xn, SA, (gk+3)&3, rowbase, gk+3, wid, prow, pcol);
  asm volatile("s_waitcnt lgkmcnt(4)" ::: "memory");   // af0c+bfc done, af1 flying
  __builtin_amdgcn_sched_barrier(0);
  __builtin_amdgcn_s_setprio(1);
  #pragma unroll
  for (int mi = 0; mi < 4; ++mi)
    #pragma unroll
    for (int n = 0; n < 4; ++n)
      acc[mi][n] = __builtin_amdgcn_mfma_f32_16x16x32_bf16(af0c[mi], bfc[n], acc[mi][n], 0, 0, 0);
  __builtin_amdgcn_s_setprio(0);
  if (gk <= 12)      asm volatile("s_waitcnt vmcnt(6)" ::: "memory");
  else if (gk == 13) asm volatile("s_waitcnt vmcnt(4)" ::: "memory");
  else if (gk == 14) asm volatile("s_waitcnt vmcnt(0)" ::: "memory");
  __builtin_amdgcn_s_barrier();                        // publishes slot gk+1

  // ---- P1: read-ahead bfr/af0(gk+1), stage B(gk+3); M1 = af1 x bfc ----
  if (gk + 1 < NGK){
    const unsigned short* SAn = &SA[((gk+1) & 3)*8192];
    const unsigned short* SBn = &SB[((gk+1) & 3)*8192];
    #pragma unroll
    for (int n = 0; n < 4; ++n)
      bfn[n] = *(const bf16x8*)&SBn[boff + n*512];
    #pragma unroll
    for (int mi = 0; mi < 4; ++mi)
      af0n[mi] = *(const bf16x8*)&SAn[aoff + mi*512];
  }
  if (gk + 3 < NGK)
    stage_slot(Xn, SB, (gk+3)&3, colbase, gk+3, wid, prow, pcol);
  if (gk + 1 < NGK) asm volatile("s_waitcnt lgkmcnt(8)" ::: "memory");  // af1 done
  else              asm volatile("s_waitcnt lgkmcnt(0)" ::: "memory");
  __builtin_amdgcn_sched_barrier(0);
  __builtin_amdgcn_s_setprio(1);
  #pragma unroll
  for (int mi = 0; mi < 4; ++mi)
    #pragma unroll
    for (int n = 0; n < 4; ++n)
      acc[4+mi][n] = __builtin_amdgcn_mfma_f32_16x16x32_bf16(af1[mi], bfc[n], acc[4+mi][n], 0, 0, 0);
  __builtin_amdgcn_s_setprio(0);
  __builtin_amdgcn_s_barrier();
}

__global__ __launch_bounds__(512, 2) void k_simlse(const unsigned short* __restrict__ Xn,
                                                   float* __restrict__ rowsumP, // [NSLOT][8192]
                                                   float* __restrict__ possim){ // [8192]
  // XCD-chunked bijective swizzle (512 = 8*64); dual-diag blocks are raw%8==0
  int bid = (blockIdx.x & 7)*64 + (blockIdx.x >> 3);

  __shared__ unsigned short SA[4*8192];   // ring: 4 slots x [256][32] bf16
  __shared__ unsigned short SB[4*8192];
  __shared__ float redR[4][256];
  __shared__ float redC[2][256];

  int tid = threadIdx.x;
  int wid = tid >> 6, l = tid & 63;
  int wr = wid >> 2, wn = wid & 3;     // 2 x 4 wave grid
  int l15 = l & 15, l4 = l >> 4;

  // staging source pre-swizzle (per-lane constants; PMC-verified 0 conflicts)
  int prow = (l >> 3)*2 + (((l & 7) ^ (l >> 3)) >> 2);
  int pcol = (((l & 7) ^ (l >> 3)) & 3) * 8;

  // ds_read frag addressing (ushort units)
  const int idx8 = (((l15 & 1) << 2) | l4) ^ (l15 >> 1);
  const int aoff = wr*4096 + (l15 >> 1)*64 + idx8*8;  // + mh*2048 + mi*512
  const int boff = wn*2048 + (l15 >> 1)*64 + idx8*8;  // + n*512

  // tile list: bid<16 -> two diagonal tiles; else one off-diagonal tile
  int ntile, rb0, cb0, rb1, cb1;
  if (bid < 16){
    ntile = 2;
    rb0 = cb0 = 2*bid;
    rb1 = cb1 = 2*bid + 1;
  } else {
    ntile = 1;
    int j = bid - 16, rbb = 0, rem = 31;
    while (j >= rem){ j -= rem; --rem; ++rbb; }
    rb0 = rbb; cb0 = rbb + 1 + j;
    rb1 = cb1 = 0;
  }

  bf16x8 af0a[4], af0b[4], bfa[4], bfb[4], af1[4];

  for (int tile = 0; tile < ntile; ++tile){
    int rb = tile ? rb1 : rb0;
    int cb = tile ? cb1 : cb0;
    int rowbase = rb*256, colbase = cb*256;
    bool diag    = (rb == cb);
    bool postile = (cb == rb + 16);

    f32x4 acc[8][4];
    #pragma unroll
    for (int m = 0; m < 8; ++m)
      #pragma unroll
      for (int n = 0; n < 4; ++n) acc[m][n] = f32x4{0.f,0.f,0.f,0.f};

    if (tile) __syncthreads();   // protect SA/SB + redR/redC reuse

    // ---- prologue: stage slots 0,1,2 (SA(g),SB(g) pairs = ledger order) ----
    #pragma unroll
    for (int g0 = 0; g0 < 3; ++g0){
      stage_slot(Xn, SA, g0, rowbase, g0, wid, prow, pcol);
      stage_slot(Xn, SB, g0, colbase, g0, wid, prow, pcol);
    }
    asm volatile("s_waitcnt vmcnt(8)" ::: "memory");   // retire slot-0 pair
    __builtin_amdgcn_s_barrier();

    // initial reads for gk=0 (order must match P1's: B then A)
    #pragma unroll
    for (int n = 0; n < 4; ++n)
      bfa[n] = *(const bf16x8*)&SB[boff + n*512];
    #pragma unroll
    for (int mi = 0; mi < 4; ++mi)
      af0a[mi] = *(const bf16x8*)&SA[aoff + mi*512];

    #pragma unroll
    for (int gk = 0; gk < NGK; gk += 2){
      gk_body(gk,   Xn, SA, SB, rowbase, colbase, wid, prow, pcol, aoff, boff,
              af0a, bfa, af0b, bfb, af1, acc);
      gk_body(gk+1, Xn, SA, SB, rowbase, colbase, wid, prow, pcol, aoff, boff,
              af0b, bfb, af0a, bfa, af1, acc);
    }

    // ---- epilogue: pos-pair grab, masks, exp, partial sums ----
    #pragma unroll
    for (int m = 0; m < 8; ++m){
      #pragma unroll
      for (int n = 0; n < 4; ++n){
        int col_l = wn*64 + n*16 + l15;
        #pragma unroll
        for (int r = 0; r < 4; ++r){
          int row_l = wr*128 + m*16 + l4*4 + r;
          float v = acc[m][n][r];
          if (postile && row_l == col_l){
            possim[rowbase + row_l] = v;
            possim[colbase + col_l] = v;
          }
          float e = __expf(v);
          if (diag && row_l == col_l) e = 0.f;
          acc[m][n][r] = e;
        }
      }
    }

    // row-sums (slot cb): reduce across 16 col-lanes
    #pragma unroll
    for (int m = 0; m < 8; ++m){
      #pragma unroll
      for (int r = 0; r < 4; ++r){
        float s = acc[m][0][r] + acc[m][1][r] + acc[m][2][r] + acc[m][3][r];
        s += __shfl_xor(s, 1); s += __shfl_xor(s, 2);
        s += __shfl_xor(s, 4); s += __shfl_xor(s, 8);
        if (l15 == 0) redR[wn][wr*128 + m*16 + l4*4 + r] = s;
      }
    }
    // col-sums (slot rb): reduce across l4 groups
    #pragma unroll
    for (int n = 0; n < 4; ++n){
      float s = 0.f;
      #pragma unroll
      for (int m = 0; m < 8; ++m)
        #pragma unroll
        for (int r = 0; r < 4; ++r) s += acc[m][n][r];
      s += __shfl_xor(s, 16); s += __shfl_xor(s, 32);
      if (l4 == 0) redC[wr][wn*64 + n*16 + l15] = s;
    }
    __syncthreads();
    if (tid < 256){
      float rs = redR[0][tid] + redR[1][tid] + redR[2][tid] + redR[3][tid];
      rowsumP[(size_t)cb*8192 + rowbase + tid] = rs;
      if (!diag){
        float cs = redC[0][tid] + redC[1][tid];
        rowsumP[(size_t)rb*8192 + colbase + tid] = cs;
      }
    }
  }
}

// ------------------- K3a: per-row lse partials (128 blocks) -----------------
__global__ __launch_bounds__(256) void k_lsepart(const float* __restrict__ rowsumP,
                                                 const float* __restrict__ possim,
                                                 float* __restrict__ part){
  int t = threadIdx.x;
  int row = blockIdx.x*64 + (t & 63);
  int g = t >> 6;
  float s = 0.f;
  #pragma unroll
  for (int cs = 0; cs < 8; ++cs)
    s += rowsumP[(size_t)(g*8 + cs)*8192 + row];
  __shared__ float partial[4][64];
  partial[g][t & 63] = s;
  __syncthreads();
  if (t < 64){
    float tot = partial[0][t] + partial[1][t] + partial[2][t] + partial[3][t];
    float v = __logf(tot) - possim[row];
    #pragma unroll
    for (int o = 32; o; o >>= 1) v += __shfl_down(v, o);
    if (t == 0) part[blockIdx.x] = v;
  }
}

// --------------------------- K3b: final combine -----------------------------
__global__ __launch_bounds__(256) void k_final(const float* __restrict__ part,
                                               const float* __restrict__ jsd_row,
                                               float* __restrict__ out){
  int t = threadIdx.x;
  float s = (t < 128) ? part[t] : 0.f;
  float j = 0.f;
  #pragma unroll
  for (int q = 0; q < 16; ++q) j += jsd_row[t + q*256];

  __shared__ float sr[4], jr[4];
  float ss = s, jj = j;
  #pragma unroll
  for (int o = 32; o; o >>= 1){ ss += __shfl_down(ss, o); jj += __shfl_down(jj, o); }
  if ((t & 63) == 0){ sr[t >> 6] = ss; jr[t >> 6] = jj; }
  __syncthreads();
  if (t == 0){
    float base = (sr[0]+sr[1]+sr[2]+sr[3]) / (8192.f * (1.f + 1e-5f));
    float jsd  = (jr[0]+jr[1]+jr[2]+jr[3]) / 4096.f;
    out[0] = base + jsd;   // LAM = 1
  }
}

// ---------------------------------------------------------------------------
extern "C" void kernel_launch(void* const* d_in, const int* in_sizes, int n_in,
                              void* d_out, int out_size, void* d_ws, size_t ws_size,
                              hipStream_t stream) {
  const float* mu     = (const float*)d_in[0];
  const float* mu_cap = (const float*)d_in[1];
  const float* lv     = (const float*)d_in[2];
  const float* lv_cap = (const float*)d_in[3];
  float* out = (float*)d_out;

  char* w = (char*)d_ws;
  unsigned short* Xn = (unsigned short*)w;                    // 8192*512*2 = 8 MB
  float* rowsumP = (float*)(w + 8388608);                     // 32*8192*4 = 1 MB
  float* possim  = (float*)(w + 8388608 + 1048576);           // 32 KB
  float* jsd_row = (float*)(w + 8388608 + 1048576 + 32768);   // 16 KB
  float* part    = (float*)(w + 8388608 + 1048576 + 32768 + 16384); // 512 B

  k_featsjsd<<<2048, 256, 0, stream>>>(mu, mu_cap, lv, lv_cap, Xn, jsd_row);
  k_simlse  <<<512,  512, 0, stream>>>(Xn, rowsumP, possim);
  k_lsepart <<<128,  256, 0, stream>>>(rowsumP, possim, part);
  k_final   <<<1,    256, 0, stream>>>(part, jsd_row, out);
}